// Round 3
// baseline (99.610 us; speedup 1.0000x reference)
//
#include <hip/hip_runtime.h>

// Fully-fused 3x Minkowski sum-pool (3x3, stride 2, pad 1) with coordinate masks.
// feat (4,1024,1024,16) f32, mask (4,1024,1024) i32 -> out = concat(c2, c3).
// Line-buffer sweep; R3: TH3=4 (1024 blocks, 4/CU), feat prefetch 2 rows deep,
// mask prefetch 4 rows deep, nontemporal output stores.

constexpr int Hh = 1024, Ww = 1024;
constexpr int TW3 = 16, TH3 = 4;           // c3 tile per block
constexpr int NU = 4 * TW3 + 3;            // 67 c1 cols computed per block
constexpr int NV = 2 * TW3 + 1;            // 33 c2 cols computed per block
constexpr int NY = TW3;                    // 16 c3 cols
constexpr int NTH = 320;
constexpr int TTMAX = 8 * TH3 + 6;         // 38 -> 39 sweep iterations

// LDS-only barrier: wait own LDS ops, sync, leave global prefetch in flight.
#define BARRIER_LDS() asm volatile("s_waitcnt lgkmcnt(0)\ns_barrier" ::: "memory")

typedef float f4_t __attribute__((ext_vector_type(4)));

__device__ inline float4 add3(const float4& a, const float4& b, const float4& c) {
    return make_float4(a.x + b.x + c.x, a.y + b.y + c.y,
                       a.z + b.z + c.z, a.w + b.w + c.w);
}
__device__ inline void st_nt(float4* p, const float4& v) {
    __builtin_nontemporal_store(*reinterpret_cast<const f4_t*>(&v),
                                reinterpret_cast<f4_t*>(p));
}

__global__ __launch_bounds__(NTH) void fused3(
    const float* __restrict__ featp, const int* __restrict__ maskp,
    float4* __restrict__ c2o, float4* __restrict__ c3o)
{
    const int j = blockIdx.x;              // col strip (c3 cols [16j,16j+16))
    const int k = blockIdx.y;              // row chunk (c3 rows [4k,4k+4))
    const int b = blockIdx.z;
    const int P0 = TW3 * j, Q0 = TH3 * k;
    const int F0 = 8 * P0 - 7;             // feat col of relative x=0
    const int T0 = 8 * Q0 - 7;             // first feat row of sweep (odd)

    const int tid = threadIdx.x;
    const int c4 = tid & 3;                // which float4 of 16 channels
    const int u  = tid >> 2;               // c1/c2/c3 col role index
    const bool aAct = tid < NU * 4;        // 268 threads: rs1/c1 role
    const bool vAct = tid < NV * 4;        // 132 threads: rs2/c2 role
    const bool yAct = tid < NY * 4;        //  64 threads: rs3/c3 role

    // double-buffered handoffs; inner stride 5 float4 (80 B) to spread banks
    __shared__ float4 c1m[2][NU][5];
    __shared__ float4 c2mS[2][NV][5];
    __shared__ unsigned char m1L[2][NU];
    __shared__ unsigned char m2L[2][NV];

    const float4* feat4 = reinterpret_cast<const float4*>(featp);
    const float4 z4 = make_float4(0.f, 0.f, 0.f, 0.f);

    auto ldMask = [&](int t, int* mm) {
#pragma unroll
        for (int dw = 0; dw < 3; ++dw) mm[dw] = 0;
        if (aAct && (unsigned)t < (unsigned)Hh) {
            const int base = (b * Hh + t) * Ww;
#pragma unroll
            for (int dw = 0; dw < 3; ++dw) {
                const int fcol = F0 + 2 * u + dw;
                if ((unsigned)fcol < (unsigned)Ww) mm[dw] = maskp[base + fcol];
            }
        }
    };
    auto ldFeat = [&](int t, const int* mm, float4* ff) {
#pragma unroll
        for (int dw = 0; dw < 3; ++dw) ff[dw] = z4;
        if (aAct && (unsigned)t < (unsigned)Hh) {
            const size_t base = (size_t)(b * Hh + t) * Ww;
#pragma unroll
            for (int dw = 0; dw < 3; ++dw) {
                const int fcol = F0 + 2 * u + dw;
                if (mm[dw])  // masked-out pixels are never fetched
                    ff[dw] = feat4[(base + fcol) * 4 + c4];
            }
        }
    };

    // pipeline: masks rows t..t+3 resident, feat rows t..t+1 resident.
    // feat row t+2 issued each iter, gated by a mask loaded 2 iters earlier.
    int mc[3], mn[3], mn2[3], mn3[3], mn4[3];
    float4 fcu[3], fn[3], fn2[3];
    ldMask(T0 + 0, mc);
    ldMask(T0 + 1, mn);
    ldMask(T0 + 2, mn2);
    ldMask(T0 + 3, mn3);
    ldFeat(T0 + 0, mc, fcu);
    ldFeat(T0 + 1, mn, fn);

    float4 h0 = z4, h1 = z4;               // rs1 history rows t-2, t-1
    int mpPrev = 0;                        // mask-pair of row t-1
    float4 r2h0 = z4, r2h1 = z4;           // rs2 history (s-2, s-1)
    float4 r3h0 = z4, r3h1 = z4;           // rs3 history (r-2, r-1)
    int m2save = 0, m3save = 0;

    for (int tt = 0; tt <= TTMAX; ++tt) {
        const int t = T0 + tt;             // feat row being consumed
        if (tt + 4 <= TTMAX) ldMask(t + 4, mn4);
        else { mn4[0] = mn4[1] = mn4[2] = 0; }
        if (tt + 2 <= TTMAX) ldFeat(t + 2, mn2, fn2);
        else { fn2[0] = fn2[1] = fn2[2] = z4; }

        // rs1[t][u] = sum_dw masked_feat[t][2u+dw]
        const float4 hc = add3(fcu[0], fcu[1], fcu[2]);
        const int mpCur = mc[1] | mc[2];   // occupancy pair (pixels 2u+1,2u+2)

        if (t & 1) {                       // c1 row s completes
            const int s = (t - 1) >> 1;
            const int sb = s & 1;
            if (aAct) {
                const int m1 = mpPrev | mpCur;
                float4 cv = z4;
                if (m1) cv = add3(h0, h1, hc);          // c1 = col-sum of rs1
                c1m[sb][u][c4] = cv;
                if (c4 == 0) m1L[sb][u] = (unsigned char)(m1 ? 1 : 0);
            }
            BARRIER_LDS();
            float4 r2c = z4; int m2 = 0;
            if (vAct) {                    // rs2[s][v] = sum_dw c1m[s][2v+dw]
                const float4 a0 = c1m[sb][2 * u + 0][c4];
                const float4 a1 = c1m[sb][2 * u + 1][c4];
                const float4 a2 = c1m[sb][2 * u + 2][c4];
                r2c = add3(a0, a1, a2);
                const int m2p = m1L[sb][2 * u + 1] | m1L[sb][2 * u + 2];
                if (s & 1) m2 = m2save | m2p; else m2save = m2p;
            }
            if ((t & 3) == 3) {            // c2 row r completes
                const int r = (t - 3) >> 2;
                const int rb = r & 1;
                if (vAct) {
                    float4 c2v = z4;
                    if (m2) c2v = add3(r2h0, r2h1, r2c);
                    if (r >= 2 * Q0 && u >= 1) {        // owned c2 rows/cols
                        const int col = 2 * P0 - 1 + u;
                        st_nt(&c2o[((size_t)((b * 256 + r) * 256 + col)) * 4 + c4], c2v);
                    }
                    c2mS[rb][u][c4] = c2v;
                    if (c4 == 0) m2L[rb][u] = (unsigned char)(m2 ? 1 : 0);
                }
                BARRIER_LDS();
                float4 r3c = z4; int m3 = 0;
                if (yAct) {                // rs3[r][y] = sum_dw c2m[r][2y+dw]
                    const float4 b0 = c2mS[rb][2 * u + 0][c4];
                    const float4 b1 = c2mS[rb][2 * u + 1][c4];
                    const float4 b2 = c2mS[rb][2 * u + 2][c4];
                    r3c = add3(b0, b1, b2);
                    const int m3p = m2L[rb][2 * u + 1] | m2L[rb][2 * u + 2];
                    if (r & 1) m3 = m3save | m3p; else m3save = m3p;
                }
                if ((t & 7) == 7) {        // c3 row q completes
                    const int q = (t - 7) >> 3;
                    if (yAct && q >= Q0) {
                        float4 c3v = z4;
                        if (m3) c3v = add3(r3h0, r3h1, r3c);
                        st_nt(&c3o[((size_t)((b * 128 + q) * 128 + P0 + u)) * 4 + c4], c3v);
                    }
                }
                r3h0 = r3h1; r3h1 = r3c;
            }
            r2h0 = r2h1; r2h1 = r2c;
        }

        h0 = h1; h1 = hc;
        mpPrev = mpCur;
        fcu[0] = fn[0];  fcu[1] = fn[1];  fcu[2] = fn[2];
        fn[0] = fn2[0];  fn[1] = fn2[1];  fn[2] = fn2[2];
        mc[0] = mn[0];   mc[1] = mn[1];   mc[2] = mn[2];
        mn[0] = mn2[0];  mn[1] = mn2[1];  mn[2] = mn2[2];
        mn2[0] = mn3[0]; mn2[1] = mn3[1]; mn2[2] = mn3[2];
        mn3[0] = mn4[0]; mn3[1] = mn4[1]; mn3[2] = mn4[2];
    }
}

extern "C" void kernel_launch(void* const* d_in, const int* in_sizes, int n_in,
                              void* d_out, int out_size, void* d_ws, size_t ws_size,
                              hipStream_t stream)
{
    const float* feat = (const float*)d_in[0];
    const int*   mask = (const int*)d_in[1];
    float4* c2 = (float4*)d_out;
    float4* c3 = c2 + (size_t)4 * 256 * 256 * 4;   // 4*256*256*16 floats ahead

    dim3 grid(Ww / (8 * TW3) /*8*/, Hh / (8 * TH3) /*32*/, 4);
    fused3<<<grid, NTH, 0, stream>>>(feat, mask, c2, c3);
}

// Round 4
// 60.826 us; speedup vs baseline: 1.6376x; 1.6376x over previous
//
#include <hip/hip_runtime.h>

// Fully-fused 3x Minkowski sum-pool (3x3, stride 2, pad 1) with coordinate masks.
// feat (4,1024,1024,16) f32, mask (4,1024,1024) i32 -> out = concat(c2, c3).
// R4: pair-row sweep — one c1 row (2 feat rows) per iteration. No register-array
// shifting, 1 int of mask history, ~half the barriers of R2.

constexpr int Hh = 1024, Ww = 1024;
constexpr int TW3 = 16, TH3 = 8;           // c3 tile per block
constexpr int NU = 4 * TW3 + 3;            // 67 c1 cols per block
constexpr int NV = 2 * TW3 + 1;            // 33 c2 cols per block
constexpr int NY = TW3;                    // 16 c3 cols
constexpr int NTH = 320;
constexpr int NS = 4 * TH3 + 3;            // 35 c1 rows per block sweep

// LDS-only barrier: wait own LDS ops, sync, leave global prefetch in flight.
#define BARRIER_LDS() asm volatile("s_waitcnt lgkmcnt(0)\ns_barrier" ::: "memory")

__device__ inline float4 add3(const float4& a, const float4& b, const float4& c) {
    return make_float4(a.x + b.x + c.x, a.y + b.y + c.y,
                       a.z + b.z + c.z, a.w + b.w + c.w);
}

__global__ __launch_bounds__(NTH) void fused3(
    const float* __restrict__ featp, const int* __restrict__ maskp,
    float4* __restrict__ c2o, float4* __restrict__ c3o)
{
    const int j = blockIdx.x;              // col strip (c3 cols [16j,16j+16))
    const int k = blockIdx.y;              // row chunk (c3 rows [8k,8k+8))
    const int b = blockIdx.z;
    const int P0 = TW3 * j, Q0 = TH3 * k;
    const int F0 = 8 * P0 - 7;             // feat col of u=0,dw=0
    const int S0 = 4 * Q0 - 3;             // first c1 row of sweep

    const int tid = threadIdx.x;
    const int c4 = tid & 3;                // which float4 of 16 channels
    const int u  = tid >> 2;               // col role index
    const bool aAct = tid < NU * 4;        // 268 threads: rs1/c1 role
    const bool vAct = tid < NV * 4;        // 132 threads: rs2/c2 role
    const bool yAct = tid < NY * 4;        //  64 threads: rs3/c3 role

    __shared__ float4 c1m[2][NU][5];       // double-buffered (write->B1->read, next write pre-B1)
    __shared__ float4 c2mS[NV][5];         // single buffer (2 barriers separate write/reuse)
    __shared__ unsigned char m1L[2][NU];
    __shared__ unsigned char m2L[NV];

    const float4* feat4 = reinterpret_cast<const float4*>(featp);
    const float4 z4 = make_float4(0.f, 0.f, 0.f, 0.f);

    auto ldMaskRow = [&](int t, int* mm) {
        mm[0] = mm[1] = mm[2] = 0;
        if (aAct && (unsigned)t < (unsigned)Hh) {
            const int base = (b * Hh + t) * Ww;
#pragma unroll
            for (int dw = 0; dw < 3; ++dw) {
                const int fc = F0 + 2 * u + dw;
                if ((unsigned)fc < (unsigned)Ww) mm[dw] = maskp[base + fc];
            }
        }
    };
    auto ldFeatRow = [&](int t, const int* mm, float4* ff) {
        ff[0] = ff[1] = ff[2] = z4;
        if (aAct && (unsigned)t < (unsigned)Hh) {
            const size_t base = (size_t)(b * Hh + t) * Ww;
#pragma unroll
            for (int dw = 0; dw < 3; ++dw) {
                if (mm[dw])   // masked-out pixels are never fetched
                    ff[dw] = feat4[(base + (F0 + 2 * u + dw)) * 4 + c4];
            }
        }
    };

    // ---- prologue: pair 0 resident, pair-1 masks resident, prev-row sum ----
    int   mA[6];        // masks of pair i+1 (entering iter i)
    float4 ffA[6];      // feat of pair i (masked)
    float4 h_prev;      // rowsum of feat row 2s-1
    int   mp_cur;       // m1 occupancy OR for pair i
    {
        int mP[3], m0[6];
        ldMaskRow(2 * S0 - 1, mP);
        ldMaskRow(2 * S0,     m0);
        ldMaskRow(2 * S0 + 1, m0 + 3);
        ldMaskRow(2 * S0 + 2, mA);
        ldMaskRow(2 * S0 + 3, mA + 3);
        float4 fP[3];
        ldFeatRow(2 * S0 - 1, mP, fP);
        ldFeatRow(2 * S0,     m0, ffA);
        ldFeatRow(2 * S0 + 1, m0 + 3, ffA + 3);
        h_prev = add3(fP[0], fP[1], fP[2]);
        mp_cur = m0[1] | m0[2] | m0[4] | m0[5];
    }

    float4 r2h0 = z4, r2h1 = z4;           // rs2 history (s-2, s-1)
    float4 r3h0 = z4, r3h1 = z4;           // rs3 history (r-2, r-1)
    int m2save = 0, m3save = 0;

    for (int i = 0; i < NS; ++i) {
        const int sb = i & 1;
        // 1. consume feat pair i -> c1 row s = S0+i
        const float4 hc_e = add3(ffA[0], ffA[1], ffA[2]);
        const float4 hc_o = add3(ffA[3], ffA[4], ffA[5]);
        if (aAct) {
            float4 cv = z4;
            if (mp_cur) cv = add3(h_prev, hc_e, hc_o);
            c1m[sb][u][c4] = cv;
            if (c4 == 0) m1L[sb][u] = (unsigned char)(mp_cur ? 1 : 0);
        }
        // 2. prefetch: feat pair i+1 (gated by mA), masks pair i+2
        const float4 hp_new = hc_o;
        const int mp_new = mA[1] | mA[2] | mA[4] | mA[5];
        const int t2 = 2 * (S0 + i) + 2;
        if (i + 1 < NS) {
            ldFeatRow(t2,     mA,     ffA);
            ldFeatRow(t2 + 1, mA + 3, ffA + 3);
        }
        if (i + 2 < NS) {
            ldMaskRow(t2 + 2, mA);
            ldMaskRow(t2 + 3, mA + 3);
        }
        // 3. c1 handoff -> rs2
        BARRIER_LDS();
        float4 r2c = z4; int m2p = 0;
        if (vAct) {
            const float4 a0 = c1m[sb][2 * u + 0][c4];
            const float4 a1 = c1m[sb][2 * u + 1][c4];
            const float4 a2 = c1m[sb][2 * u + 2][c4];
            r2c = add3(a0, a1, a2);
            m2p = m1L[sb][2 * u + 1] | m1L[sb][2 * u + 2];
        }
        if ((i & 1) == 0) {
            // c2 row r = 2*Q0 - 2 + i/2 completes
            const int r = 2 * Q0 - 2 + (i >> 1);
            if (vAct) {
                const int m2 = m2save | m2p;
                float4 c2v = z4;
                if (m2) c2v = add3(r2h0, r2h1, r2c);
                if (i >= 4 && u >= 1)   // owned rows r>=2Q0, owned cols
                    c2o[((size_t)((b * 256 + r) * 256 + (2 * P0 - 1 + u))) * 4 + c4] = c2v;
                c2mS[u][c4] = c2v;
                if (c4 == 0) m2L[u] = (unsigned char)(m2 ? 1 : 0);
            }
            BARRIER_LDS();
            float4 r3c = z4; int m3p = 0;
            if (yAct) {
                const float4 b0 = c2mS[2 * u + 0][c4];
                const float4 b1 = c2mS[2 * u + 1][c4];
                const float4 b2 = c2mS[2 * u + 2][c4];
                r3c = add3(b0, b1, b2);
                m3p = m2L[2 * u + 1] | m2L[2 * u + 2];
            }
            if ((i & 2) == 0) {          // r even: save
                m3save = m3p;
            } else if (yAct && i >= 6) { // r odd: c3 row q completes
                const int m3 = m3save | m3p;
                float4 c3v = z4;
                if (m3) c3v = add3(r3h0, r3h1, r3c);
                const int q = Q0 + ((i - 6) >> 2);
                c3o[((size_t)((b * 128 + q) * 128 + (P0 + u))) * 4 + c4] = c3v;
            }
            r3h0 = r3h1; r3h1 = r3c;
        } else {
            m2save = m2p;                // s = 2r: save for next completion
        }
        r2h0 = r2h1; r2h1 = r2c;
        h_prev = hp_new; mp_cur = mp_new;
    }
}

extern "C" void kernel_launch(void* const* d_in, const int* in_sizes, int n_in,
                              void* d_out, int out_size, void* d_ws, size_t ws_size,
                              hipStream_t stream)
{
    const float* feat = (const float*)d_in[0];
    const int*   mask = (const int*)d_in[1];
    float4* c2 = (float4*)d_out;
    float4* c3 = c2 + (size_t)4 * 256 * 256 * 4;   // 4*256*256*16 floats ahead

    dim3 grid(Ww / (8 * TW3) /*8*/, Hh / (8 * TH3) /*16*/, 4);
    fused3<<<grid, NTH, 0, stream>>>(feat, mask, c2, c3);
}